// Round 17
// baseline (61.259 us; speedup 1.0000x reference)
//
#include <hip/hip_runtime.h>
#include <hip/hip_bf16.h>
#include <math.h>

#define NROWS 16384
#define DIN   784
#define DZ    100
#define NS    10
#define NCT   16           // 16 col-tiles x 16 = 256 cols (200 real + 56 zero pad)
#define KTILES 25          // 25 * 32 = 800 >= 784, tail frags zeroed
#define BND_THR 45.0f
#define KTPAD 520          // kt-stride in ushorts (1040B) for the LDS tile
#define BMI   32           // colmean block rows

typedef unsigned short ushort_t;
typedef short bf16x8 __attribute__((ext_vector_type(8)));
typedef float f32x4  __attribute__((ext_vector_type(4)));

// ws: [0..199] colsums (atomic)  [200] pv sum  [203] done-counter
//     [208..8047] y2[s][i] = y*log2e (f32, for pv slow path)
// byte 64KB..: Wb bf16 frag-swizzled W (400 KB)
// byte 1MB..:  Xf bf16 A-frags of x, 1024*25*512 ushorts (26.2 MB)
//              (capacity proven in R10/R11: the Xf path executed on this harness)
#define WS_Y2 208
#define WB_OFF_BYTES (64u * 1024u)
#define XF_OFF_BYTES (1024u * 1024u)

__device__ __forceinline__ float softplus_fast(float v) {
    // ln(1+e^v) = (max(t,0) + log2(1+2^-|t|)) * ln2, t = v*log2e
    float t = v * 1.44269504088896f;
    return (fmaxf(t, 0.f)
            + __builtin_amdgcn_logf(1.f + __builtin_amdgcn_exp2f(-fabsf(t))))
           * 0.69314718055995f;
}
__device__ __forceinline__ unsigned pack2(float lo, float hi) {
    float2 f2; f2.x = lo; f2.y = hi;
    __hip_bfloat162 h2 = __float22bfloat162_rn(f2);
    return *reinterpret_cast<unsigned*>(&h2);
}

// ---- W -> bf16 B-frags + ws zero ----
// Wb[((kt*16 + ct)*64 + l)*8 + j] = W[ct*16 + (l&15)][kt*32 + (l>>4)*8 + j]
__global__ __launch_bounds__(256) void wb_kernel(
    const float* __restrict__ W0, const float* __restrict__ W1,
    ushort_t* __restrict__ Wb, float* __restrict__ ws)
{
    if (blockIdx.x == 0) ws[threadIdx.x] = 0.f;    // sums + counters
    int t = blockIdx.x * 256 + threadIdx.x;
    if (t >= KTILES * NCT * 64) return;
    int kt = t >> 10;
    int r  = t & 1023;
    int ct = r >> 6, l = r & 63;
    int col = ct * 16 + (l & 15);
    int k0  = kt * 32 + (l >> 4) * 8;
    uint4 o = make_uint4(0u, 0u, 0u, 0u);
    if (col < 200 && k0 < DIN) {
        const float* src = (col < 100 ? W0 + (size_t)col * DIN
                                      : W1 + (size_t)(col - 100) * DIN) + k0;
        float4 a = *(const float4*)src;
        float4 b = *(const float4*)(src + 4);
        o.x = pack2(a.x, a.y); o.y = pack2(a.z, a.w);
        o.z = pack2(b.x, b.y); o.w = pack2(b.z, b.w);
    }
    *(uint4*)(Wb + (size_t)t * 8) = o;
}

// ---- colmean i: BM=32, 2 blocks/CU overlap, B-stationary 2ct/wave,
//      + coalesced Xf frag writeout (feeds pv; kills pv's scattered x re-read) ----
__global__ __launch_bounds__(512) void colmean_i(
    const float* __restrict__ x, const ushort_t* __restrict__ Wb,
    const float* __restrict__ b0, const float* __restrict__ b1,
    float* __restrict__ ws, ushort_t* __restrict__ Xf)
{
    __shared__ ushort_t xls[2 * KTILES * KTPAD];   // 52 KB -> 2 blocks/CU
    const int tid = threadIdx.x;
    const int lane = tid & 63, w = tid >> 6;
    const int row0 = blockIdx.x * BMI;

    // ---- stage: coalesced x float4 reads -> bf16 A-frags in LDS, ONE barrier ----
    for (int slot = tid; slot < 3200; slot += 512) {   // slot = r*100 + kt*4 + kc
        int r  = slot / 100;
        int sl = slot - r * 100;
        int kt = sl >> 2, kc = sl & 3;
        int k0 = kt * 32 + kc * 8;
        uint4 o = make_uint4(0u, 0u, 0u, 0u);
        if (k0 + 8 <= DIN) {
            const float* src = x + (size_t)(row0 + r) * DIN + k0;
            float4 a = *(const float4*)src, b = *(const float4*)(src + 4);
            o.x = pack2(a.x, a.y); o.y = pack2(a.z, a.w);
            o.z = pack2(b.x, b.y); o.w = pack2(b.z, b.w);
        }
        int l = (kc << 4) | (r & 15);
        *(uint4*)&xls[((size_t)(r >> 4) * KTILES + kt) * KTPAD + l * 8] = o;
    }
    __syncthreads();

    // ---- Xf writeout: LDS -> global, fully coalesced (1KB runs per wave) ----
    // Xf[((rt16*25 + kt)*64 + l)*8 + j]; rt16 = 2*blockIdx + rt
    for (int idx = tid; idx < 3200; idx += 512) {      // idx = rt*1600 + kt*64 + l
        int rt  = idx / 1600;
        int rem = idx - rt * 1600;
        int kt = rem >> 6, l = rem & 63;
        uint4 v = *(const uint4*)&xls[((size_t)rt * KTILES + kt) * KTPAD + l * 8];
        *(uint4*)(Xf + (((size_t)(2 * blockIdx.x + rt) * KTILES + kt) * 64 + l) * 8) = v;
    }

    // ---- K-loop: zero barriers, named reg dbuf; wave owns ct {2w,2w+1} x both rt ----
    const int ct0 = w * 2;
    const ushort_t* a0p = xls + lane * 8;                    // rt0
    const ushort_t* a1p = xls + KTILES * KTPAD + lane * 8;   // rt1
    const ushort_t* wbp = Wb + (size_t)ct0 * 512 + lane * 8;

    f32x4 acc00 = (f32x4){0.f,0.f,0.f,0.f}, acc01 = acc00;
    f32x4 acc10 = acc00, acc11 = acc00;

    bf16x8 A0a, A1a, A0b, A1b;
    uint4  B0a, B1a, B0b, B1b;

    auto ld = [&](int kt, bf16x8& A0, bf16x8& A1, uint4& B0, uint4& B1) {
        A0 = *(const bf16x8*)(a0p + (size_t)kt * KTPAD);
        A1 = *(const bf16x8*)(a1p + (size_t)kt * KTPAD);
        B0 = *(const uint4*)(wbp + (size_t)kt * 8192);
        B1 = *(const uint4*)(wbp + (size_t)kt * 8192 + 512);
    };
    auto cp = [&](const bf16x8& A0, const bf16x8& A1, const uint4& B0, const uint4& B1) {
        bf16x8 f0 = *(const bf16x8*)&B0, f1 = *(const bf16x8*)&B1;
        acc00 = __builtin_amdgcn_mfma_f32_16x16x32_bf16(A0, f0, acc00, 0, 0, 0);
        acc01 = __builtin_amdgcn_mfma_f32_16x16x32_bf16(A0, f1, acc01, 0, 0, 0);
        acc10 = __builtin_amdgcn_mfma_f32_16x16x32_bf16(A1, f0, acc10, 0, 0, 0);
        acc11 = __builtin_amdgcn_mfma_f32_16x16x32_bf16(A1, f1, acc11, 0, 0, 0);
    };

    ld(0, A0a, A1a, B0a, B1a);
    for (int i = 0; i < 12; ++i) {
        ld(2 * i + 1, A0b, A1b, B0b, B1b);
        cp(A0a, A1a, B0a, B1a);
        ld(2 * i + 2, A0a, A1a, B0a, B1a);
        cp(A0b, A1b, B0b, B1b);
    }
    cp(A0a, A1a, B0a, B1a);                // kt = 24

    // ---- epilogue: wave owns complete 32-row sums for its 2 col-tiles ----
    const int jcol = lane & 15;
#pragma unroll
    for (int ctl = 0; ctl < 2; ++ctl) {
        int j = (ct0 + ctl) * 16 + jcol;
        float bias = (j < 100) ? b0[j] : ((j < 200) ? b1[j - 100] : 0.f);
        f32x4 u0 = ctl ? acc01 : acc00;
        f32x4 u1 = ctl ? acc11 : acc10;
        float v = 0.f;
#pragma unroll
        for (int r = 0; r < 4; ++r)
            v += softplus_fast(u0[r] + bias) + softplus_fast(u1[r] + bias);
        v += __shfl_xor(v, 16);
        v += __shfl_xor(v, 32);
        if ((lane >> 4) == 0 && j < 200) atomicAdd(&ws[j], v);
    }
}

// ---- y2 = (z @ W2.T + b2) * log2e with z computed inline from colsums ----
__global__ __launch_bounds__(256) void y2z_kernel(
    const float* __restrict__ W2, const float* __restrict__ b2,
    const float* __restrict__ eps, float* __restrict__ ws)
{
    int wid  = (int)((blockIdx.x * 256 + threadIdx.x) >> 6);
    int lane = threadIdx.x & 63;
    if (wid >= NS * DIN) return;
    int s = wid / DIN, i = wid % DIN;
    const float inv = 1.f / (float)NROWS;
    const float* wr = W2 + (size_t)i * DZ;
    const float* er = eps + (size_t)s * DZ;
    float p = 0.f;
    for (int d = lane; d < DZ; d += 64) {
        float zd = inv * (ws[d] + ws[100 + d] * er[d]);
        p += zd * wr[d];
    }
#pragma unroll
    for (int off = 32; off > 0; off >>= 1) p += __shfl_xor(p, off);
    if (lane == 0) ws[WS_Y2 + wid] = (p + b2[i]) * 1.4426950408889634f;
}

// ---- pv + fused finalization: consumes Xf frags (coalesced), R10/R11-proven ustep ----
// MFMA-certified bound: sum_i max(u,0) = 0.5*(n.y + |n|.|y|), u=(1-2x)*y2 (log2).
// bnd >= 45 => p < 2^-43 << ulp(0.001)/2 => term == ln(0.001) exactly.
__global__ __launch_bounds__(256, 4) void pv_final_kernel(
    const float* __restrict__ x, float* __restrict__ ws,
    const ushort_t* __restrict__ Xf,
    const float* __restrict__ eps, float* __restrict__ out, int nblocks)
{
    __shared__ ushort_t yf[KTILES * 512];   // y2 B-frags (bf16)
    __shared__ ushort_t ya[KTILES * 512];   // |y2| B-frags
    __shared__ float bsum;
    __shared__ int lastflag;
    __shared__ float dred[256];
    const int tid = threadIdx.x;
    const int lane = tid & 63, w = tid >> 6;

    for (int idx = tid; idx < KTILES * 64; idx += 256) {
        int kt = idx >> 6, l = idx & 63;
        int ss = l & 15, k0 = kt * 32 + (l >> 4) * 8;
        uint4 o = make_uint4(0u, 0u, 0u, 0u), oa = o;
        if (ss < NS && k0 < DIN) {
            const float* src = ws + WS_Y2 + ss * DIN + k0;
            float4 a = *(const float4*)src, b = *(const float4*)(src + 4);
            o.x = pack2(a.x, a.y); o.y = pack2(a.z, a.w);
            o.z = pack2(b.x, b.y); o.w = pack2(b.z, b.w);
            oa.x = o.x & 0x7FFF7FFFu; oa.y = o.y & 0x7FFF7FFFu;
            oa.z = o.z & 0x7FFF7FFFu; oa.w = o.w & 0x7FFF7FFFu;
        }
        *(uint4*)(yf + (size_t)idx * 8) = o;
        *(uint4*)(ya + (size_t)idx * 8) = oa;
    }
    if (tid == 0) { bsum = 0.f; lastflag = 0; }
    __syncthreads();

    const int tile = blockIdx.x * 4 + w;       // 1024 tiles of 16 rows
    const int s    = lane & 15;
    const ushort_t* xfp = Xf + (size_t)tile * KTILES * 512 + lane * 8;
    const float L001 = -6.90775527898f;        // ln(0.001f)

    f32x4 acc0 = (f32x4){0.f, 0.f, 0.f, 0.f};
    f32x4 acc1 = (f32x4){0.f, 0.f, 0.f, 0.f};

    auto comp = [&](int kt, const uint4& X) {
        bf16x8 nf; unsigned* p = (unsigned*)&nf;
        const unsigned* xw = (const unsigned*)&X;
#pragma unroll
        for (int i2 = 0; i2 < 4; ++i2) {
            float lo = __uint_as_float(xw[i2] << 16);
            float hi = __uint_as_float(xw[i2] & 0xFFFF0000u);
            p[i2] = pack2(1.f - 2.f * lo, 1.f - 2.f * hi);
        }
        bf16x8 na; unsigned* q = (unsigned*)&na;
        q[0] = p[0] & 0x7FFF7FFFu; q[1] = p[1] & 0x7FFF7FFFu;
        q[2] = p[2] & 0x7FFF7FFFu; q[3] = p[3] & 0x7FFF7FFFu;
        bf16x8 fy = *(const bf16x8*)(yf + (size_t)kt * 512 + lane * 8);
        bf16x8 fa = *(const bf16x8*)(ya + (size_t)kt * 512 + lane * 8);
        acc0 = __builtin_amdgcn_mfma_f32_16x16x32_bf16(nf, fy, acc0, 0, 0, 0);
        acc1 = __builtin_amdgcn_mfma_f32_16x16x32_bf16(na, fa, acc1, 0, 0, 0);
    };

    uint4 Xa, Xb;
    Xa = *(const uint4*)(xfp);
    for (int i = 0; i < 12; ++i) {
        Xb = *(const uint4*)(xfp + (size_t)(2 * i + 1) * 512);
        comp(2 * i, Xa);
        Xa = *(const uint4*)(xfp + (size_t)(2 * i + 2) * 512);
        comp(2 * i + 1, Xb);
    }
    comp(24, Xa);

    float bnd[4];
#pragma unroll
    for (int r = 0; r < 4; ++r) bnd[r] = 0.5f * (acc0[r] + acc1[r]);
    float wsum;
    bool lslow = (s < NS) &&
        (fminf(fminf(bnd[0], bnd[1]), fminf(bnd[2], bnd[3])) < BND_THR);
    unsigned long long m = __ballot(lslow);
    if (m == 0ull) {
        wsum = 160.f * L001;                   // 16 rows x 10 samples, all certified
    } else {
        int nslow = 0;
        float slowsum = 0.f;
#pragma unroll
        for (int r = 0; r < 4; ++r) {
            unsigned long long mr = __ballot((s < NS) && (bnd[r] < BND_THR));
            nslow += (int)__popcll(mr);
            while (mr) {
                int src = (int)__ffsll(mr) - 1; mr &= (mr - 1);
                int ss = src & 15;
                int rrow = tile * 16 + (src >> 4) * 4 + r;
                const float* xq = x + (size_t)rrow * DIN;
                const float* yq = ws + WS_Y2 + ss * DIN;
                float a = 0.f;
                for (int i = lane; i < DIN; i += 64)
                    a -= __builtin_amdgcn_logf(
                        1.f + __builtin_amdgcn_exp2f((1.f - 2.f * xq[i]) * yq[i]));
#pragma unroll
                for (int off = 32; off > 0; off >>= 1) a += __shfl_xor(a, off);
                slowsum += __logf(__builtin_amdgcn_exp2f(a) + 0.001f);
            }
        }
        wsum = (float)(160 - nslow) * L001 + slowsum;
    }
    if (lane == 0) atomicAdd(&bsum, wsum);
    __syncthreads();

    // ---- completion protocol: last block computes Dkl + output ----
    if (tid == 0) {
        atomicAdd(&ws[200], bsum);
        __threadfence();
        unsigned old = atomicAdd((unsigned*)&ws[203], 1u);
        if (old == (unsigned)(nblocks - 1)) lastflag = 1;
    }
    __syncthreads();
    if (lastflag) {
        __threadfence();
        float contrib = 0.f;
        if (tid < DZ) {
            const float inv = 1.f / (float)NROWS;
            float mm = ws[tid] * inv;
            float cc = ws[100 + tid] * inv;
            contrib = 0.5f * __logf(cc);
#pragma unroll
            for (int ss2 = 0; ss2 < NS; ++ss2) {
                float e = eps[ss2 * DZ + tid];
                float zz = mm + cc * e;
                contrib += (0.5f * cc * e * e - 0.5f * zz * zz) * (1.f / NS);
            }
        }
        dred[tid] = contrib;
        __syncthreads();
        for (int off = 128; off > 0; off >>= 1) {
            if (tid < off) dred[tid] += dred[tid + off];
            __syncthreads();
        }
        if (tid == 0) {
            float S = atomicAdd(&ws[200], 0.f);
            float E = S * (1.f / ((float)NROWS * (float)NS));
            out[0] = -(E + dred[0]);
        }
    }
}

extern "C" void kernel_launch(void* const* d_in, const int* in_sizes, int n_in,
                              void* d_out, int out_size, void* d_ws, size_t ws_size,
                              hipStream_t stream)
{
    const float* x   = (const float*)d_in[0];
    const float* W0  = (const float*)d_in[1];
    const float* b0  = (const float*)d_in[2];
    const float* W1  = (const float*)d_in[3];
    const float* b1  = (const float*)d_in[4];
    const float* W2  = (const float*)d_in[5];
    const float* b2  = (const float*)d_in[6];
    const float* eps = (const float*)d_in[7];
    float* out = (float*)d_out;
    float* ws  = (float*)d_ws;
    ushort_t* Wb = (ushort_t*)((char*)d_ws + WB_OFF_BYTES);
    ushort_t* Xf = (ushort_t*)((char*)d_ws + XF_OFF_BYTES);

    wb_kernel<<<(KTILES * NCT * 64 + 255) / 256, 256, 0, stream>>>(W0, W1, Wb, ws);
    colmean_i<<<NROWS / BMI, 512, 0, stream>>>(x, Wb, b0, b1, ws, Xf);
    y2z_kernel<<<(NS * DIN * 64) / 256, 256, 0, stream>>>(W2, b2, eps, ws);
    pv_final_kernel<<<256, 256, 0, stream>>>(x, ws, Xf, eps, out, 256);
}

// Round 18
// 53.969 us; speedup vs baseline: 1.1351x; 1.1351x over previous
//
#include <hip/hip_runtime.h>
#include <hip/hip_bf16.h>
#include <math.h>

#define NROWS 16384
#define DIN   784
#define DZ    100
#define NS    10
#define NCT   16           // 16 col-tiles x 16 = 256 cols (200 real + 56 zero pad)
#define KTILES 25          // 25 * 32 = 800 >= 784, tail frags zeroed
#define BND_THR 45.0f
#define KTPAD 520          // frag-set stride in ushorts (1040B): bank-spread
#define CH    5            // kts per chunk
#define NCH   5            // chunks (5*5 = 25)

typedef unsigned short ushort_t;
typedef short bf16x8 __attribute__((ext_vector_type(8)));
typedef float f32x4  __attribute__((ext_vector_type(4)));

// ws: [0..199] colsums (atomic)  [200] pv sum  [203] done-counter
//     [208..8047] y2[s][i] = y*log2e
// byte 64KB..: Wb bf16 frag-swizzled W (400 KB)
#define WS_Y2 208
#define WB_OFF_BYTES (64u * 1024u)

__device__ __forceinline__ float softplus_fast(float v) {
    // ln(1+e^v) = (max(t,0) + log2(1+2^-|t|)) * ln2, t = v*log2e
    float t = v * 1.44269504088896f;
    return (fmaxf(t, 0.f)
            + __builtin_amdgcn_logf(1.f + __builtin_amdgcn_exp2f(-fabsf(t))))
           * 0.69314718055995f;
}
__device__ __forceinline__ unsigned pack2(float lo, float hi) {
    float2 f2; f2.x = lo; f2.y = hi;
    __hip_bfloat162 h2 = __float22bfloat162_rn(f2);
    return *reinterpret_cast<unsigned*>(&h2);
}

// ---- W -> bf16 B-frags + ws zero ----
// Wb[((kt*16 + ct)*64 + l)*8 + j] = W[ct*16 + (l&15)][kt*32 + (l>>4)*8 + j]
__global__ __launch_bounds__(256) void wb_kernel(
    const float* __restrict__ W0, const float* __restrict__ W1,
    ushort_t* __restrict__ Wb, float* __restrict__ ws)
{
    if (blockIdx.x == 0) ws[threadIdx.x] = 0.f;    // sums + counters
    int t = blockIdx.x * 256 + threadIdx.x;
    if (t >= KTILES * NCT * 64) return;
    int kt = t >> 10;
    int r  = t & 1023;
    int ct = r >> 6, l = r & 63;
    int col = ct * 16 + (l & 15);
    int k0  = kt * 32 + (l >> 4) * 8;
    uint4 o = make_uint4(0u, 0u, 0u, 0u);
    if (col < 200 && k0 < DIN) {
        const float* src = (col < 100 ? W0 + (size_t)col * DIN
                                      : W1 + (size_t)(col - 100) * DIN) + k0;
        float4 a = *(const float4*)src;
        float4 b = *(const float4*)(src + 4);
        o.x = pack2(a.x, a.y); o.y = pack2(a.z, a.w);
        o.z = pack2(b.x, b.y); o.w = pack2(b.z, b.w);
    }
    *(uint4*)(Wb + (size_t)t * 8) = o;
}

// ---- colmean k: BM=64 B-stationary waves + chunked double-buffered stage ----
// 256 blocks x 1024 thr (16 waves). Wave w owns col-tile w for all 4 rowtiles.
// K split into 5 chunks of 5 kt; chunk c+1's x-loads issue BEFORE chunk c's
// compute (T14: global->regs early, vmcnt+ds_write late). LDS 41.6 KB -> 2
// blocks/CU; 1 barrier/chunk. Per chunk/wave: 5 B-glob + 20 ds_read + 20 MFMA.
__global__ __launch_bounds__(1024) void colmean_k(
    const float* __restrict__ x, const ushort_t* __restrict__ Wb,
    const float* __restrict__ b0, const float* __restrict__ b1,
    float* __restrict__ ws)
{
    __shared__ ushort_t xch[2][4 * CH * KTPAD];    // 2 x 20.8 KB
    const int tid = threadIdx.x;
    const int lane = tid & 63, w = tid >> 6;

    int b = blockIdx.x;                            // XCD-bijective: 256 = 8 * 32
    int logical = (b & 7) * 32 + (b >> 3);
    const int row0 = logical * 64;
    const float* xr = x + (size_t)row0 * DIN;

    // slot = r*20 + kt_l*4 + kc  (64 rows x 5 kt x 4 kc = 1280 slots; 8 floats each)
    auto stage_load = [&](int ck, int slot, uint4& s, int& doff) {
        int r = slot / 20;
        int rem = slot - r * 20;
        int kt_l = rem >> 2, kc = rem & 3;
        int k0 = (ck * CH + kt_l) * 32 + kc * 8;
        uint4 o = make_uint4(0u, 0u, 0u, 0u);
        if (k0 + 8 <= DIN) {
            const float* src = xr + (size_t)r * DIN + k0;
            float4 a = *(const float4*)src, bb = *(const float4*)(src + 4);
            o.x = pack2(a.x, a.y); o.y = pack2(a.z, a.w);
            o.z = pack2(bb.x, bb.y); o.w = pack2(bb.z, bb.w);
        }
        s = o;
        int l = (kc << 4) | (r & 15);
        doff = ((r >> 4) * CH + kt_l) * KTPAD + l * 8;
    };

    f32x4 acc0 = (f32x4){0.f,0.f,0.f,0.f}, acc1 = acc0, acc2 = acc0, acc3 = acc0;
    const ushort_t* wbp = Wb + (size_t)w * 512 + lane * 8;   // + kt*8192

    auto compute = [&](int ck, int buf) {
        const ushort_t* ap = xch[buf] + lane * 8;
        uint4 Ba = *(const uint4*)(wbp + (size_t)(ck * CH) * 8192);
#pragma unroll
        for (int kt_l = 0; kt_l < CH; ++kt_l) {
            uint4 Bb;
            if (kt_l + 1 < CH)
                Bb = *(const uint4*)(wbp + (size_t)(ck * CH + kt_l + 1) * 8192);
            bf16x8 bf = *(const bf16x8*)&Ba;
            bf16x8 A0 = *(const bf16x8*)(ap + (size_t)(0 * CH + kt_l) * KTPAD);
            bf16x8 A1 = *(const bf16x8*)(ap + (size_t)(1 * CH + kt_l) * KTPAD);
            bf16x8 A2 = *(const bf16x8*)(ap + (size_t)(2 * CH + kt_l) * KTPAD);
            bf16x8 A3 = *(const bf16x8*)(ap + (size_t)(3 * CH + kt_l) * KTPAD);
            acc0 = __builtin_amdgcn_mfma_f32_16x16x32_bf16(A0, bf, acc0, 0, 0, 0);
            acc1 = __builtin_amdgcn_mfma_f32_16x16x32_bf16(A1, bf, acc1, 0, 0, 0);
            acc2 = __builtin_amdgcn_mfma_f32_16x16x32_bf16(A2, bf, acc2, 0, 0, 0);
            acc3 = __builtin_amdgcn_mfma_f32_16x16x32_bf16(A3, bf, acc3, 0, 0, 0);
            Ba = Bb;
        }
    };

    // prologue: stage chunk 0
    {
        uint4 s0, s1; int d0, d1;
        stage_load(0, tid, s0, d0);
        bool two = (tid < 1280 - 1024);
        if (two) stage_load(0, tid + 1024, s1, d1);
        *(uint4*)&xch[0][d0] = s0;
        if (two) *(uint4*)&xch[0][d1] = s1;
    }
    __syncthreads();

    int cur = 0;
#pragma unroll 1
    for (int ck = 0; ck < NCH; ++ck) {
        uint4 s0, s1; int d0, d1;
        const bool more = (ck + 1 < NCH);
        const bool two = (tid < 1280 - 1024);
        if (more) {                                 // issue next chunk's loads NOW
            stage_load(ck + 1, tid, s0, d0);
            if (two) stage_load(ck + 1, tid + 1024, s1, d1);
        }
        compute(ck, cur);                           // overlaps in-flight loads
        if (more) {                                 // waitcnt lands here, then write
            *(uint4*)&xch[cur ^ 1][d0] = s0;
            if (two) *(uint4*)&xch[cur ^ 1][d1] = s1;
        }
        __syncthreads();
        cur ^= 1;
    }

    // ---- epilogue: wave owns complete 64-row sums for its 16 cols ----
    const int j = w * 16 + (lane & 15);
    const float bias = (j < 100) ? b0[j] : ((j < 200) ? b1[j - 100] : 0.f);
    float v = 0.f;
#pragma unroll
    for (int r = 0; r < 4; ++r)
        v += softplus_fast(acc0[r] + bias) + softplus_fast(acc1[r] + bias)
           + softplus_fast(acc2[r] + bias) + softplus_fast(acc3[r] + bias);
    v += __shfl_xor(v, 16);
    v += __shfl_xor(v, 32);
    if ((lane >> 4) == 0 && j < 200) atomicAdd(&ws[j], v);
}

// ---- y2 = (z @ W2.T + b2) * log2e with z computed inline from colsums ----
__global__ __launch_bounds__(256) void y2z_kernel(
    const float* __restrict__ W2, const float* __restrict__ b2,
    const float* __restrict__ eps, float* __restrict__ ws)
{
    int wid  = (int)((blockIdx.x * 256 + threadIdx.x) >> 6);
    int lane = threadIdx.x & 63;
    if (wid >= NS * DIN) return;
    int s = wid / DIN, i = wid % DIN;
    const float inv = 1.f / (float)NROWS;
    const float* wr = W2 + (size_t)i * DZ;
    const float* er = eps + (size_t)s * DZ;
    float p = 0.f;
    for (int d = lane; d < DZ; d += 64) {
        float zd = inv * (ws[d] + ws[100 + d] * er[d]);
        p += zd * wr[d];
    }
#pragma unroll
    for (int off = 32; off > 0; off >>= 1) p += __shfl_xor(p, off);
    if (lane == 0) ws[WS_Y2 + wid] = (p + b2[i]) * 1.4426950408889634f;
}

// ---- pv + fused finalization (R16-proven, direct x) ----
// MFMA-certified bound: sum_i max(u,0) = 0.5*(n.y + |n|.|y|), u=(1-2x)*y2 (log2).
// bnd >= 45 => p < 2^-43 << ulp(0.001)/2 => term == ln(0.001) exactly.
__global__ __launch_bounds__(256, 4) void pv_final_kernel(
    const float* __restrict__ x, float* __restrict__ ws,
    const float* __restrict__ eps, float* __restrict__ out, int nblocks)
{
    __shared__ ushort_t yf[KTILES * 512];   // y2 B-frags (bf16)
    __shared__ ushort_t ya[KTILES * 512];   // |y2| B-frags
    __shared__ float bsum;
    __shared__ int lastflag;
    __shared__ float dred[256];
    const int tid = threadIdx.x;
    const int lane = tid & 63, w = tid >> 6;

    for (int idx = tid; idx < KTILES * 64; idx += 256) {
        int kt = idx >> 6, l = idx & 63;
        int ss = l & 15, k0 = kt * 32 + (l >> 4) * 8;
        uint4 o = make_uint4(0u, 0u, 0u, 0u), oa = o;
        if (ss < NS && k0 < DIN) {
            const float* src = ws + WS_Y2 + ss * DIN + k0;
            float4 a = *(const float4*)src, b = *(const float4*)(src + 4);
            o.x = pack2(a.x, a.y); o.y = pack2(a.z, a.w);
            o.z = pack2(b.x, b.y); o.w = pack2(b.z, b.w);
            oa.x = o.x & 0x7FFF7FFFu; oa.y = o.y & 0x7FFF7FFFu;
            oa.z = o.z & 0x7FFF7FFFu; oa.w = o.w & 0x7FFF7FFFu;
        }
        *(uint4*)(yf + (size_t)idx * 8) = o;
        *(uint4*)(ya + (size_t)idx * 8) = oa;
    }
    if (tid == 0) { bsum = 0.f; lastflag = 0; }
    __syncthreads();

    const int tile = blockIdx.x * 4 + w;       // 1024 tiles of 16 rows
    const int row  = tile * 16 + (lane & 15);
    const int kc   = lane >> 4;
    const int s    = lane & 15;
    const float* xp = x + (size_t)row * DIN;
    const float L001 = -6.90775527898f;        // ln(0.001f)

    f32x4 acc0 = (f32x4){0.f, 0.f, 0.f, 0.f};
    f32x4 acc1 = (f32x4){0.f, 0.f, 0.f, 0.f};
    float4 a0A, a1A, a0B, a1B;

    auto loadA = [&](int kt, float4& a0, float4& a1) {
        int k0 = kt * 32 + kc * 8;
        if (k0 + 8 > DIN) k0 = 768;            // junk ok: y frags zero there
        a0 = *(const float4*)(xp + k0);
        a1 = *(const float4*)(xp + k0 + 4);
    };
    auto comp = [&](int kt, const float4& a0, const float4& a1) {
        bf16x8 nf; unsigned* p = (unsigned*)&nf;
        p[0] = pack2(1.f - 2.f * a0.x, 1.f - 2.f * a0.y);
        p[1] = pack2(1.f - 2.f * a0.z, 1.f - 2.f * a0.w);
        p[2] = pack2(1.f - 2.f * a1.x, 1.f - 2.f * a1.y);
        p[3] = pack2(1.f - 2.f * a1.z, 1.f - 2.f * a1.w);
        bf16x8 na; unsigned* q = (unsigned*)&na;
        q[0] = p[0] & 0x7FFF7FFFu; q[1] = p[1] & 0x7FFF7FFFu;
        q[2] = p[2] & 0x7FFF7FFFu; q[3] = p[3] & 0x7FFF7FFFu;
        bf16x8 fy = *(const bf16x8*)(yf + (size_t)kt * 512 + lane * 8);
        bf16x8 fa = *(const bf16x8*)(ya + (size_t)kt * 512 + lane * 8);
        acc0 = __builtin_amdgcn_mfma_f32_16x16x32_bf16(nf, fy, acc0, 0, 0, 0);
        acc1 = __builtin_amdgcn_mfma_f32_16x16x32_bf16(na, fa, acc1, 0, 0, 0);
    };
    loadA(0, a0A, a1A);
    for (int i = 0; i < 12; ++i) {
        loadA(2 * i + 1, a0B, a1B);
        comp(2 * i, a0A, a1A);
        loadA(2 * i + 2, a0A, a1A);
        comp(2 * i + 1, a0B, a1B);
    }
    comp(24, a0A, a1A);

    float bnd[4];
#pragma unroll
    for (int r = 0; r < 4; ++r) bnd[r] = 0.5f * (acc0[r] + acc1[r]);
    float wsum;
    bool lslow = (s < NS) &&
        (fminf(fminf(bnd[0], bnd[1]), fminf(bnd[2], bnd[3])) < BND_THR);
    unsigned long long m = __ballot(lslow);
    if (m == 0ull) {
        wsum = 160.f * L001;                   // 16 rows x 10 samples, all certified
    } else {
        int nslow = 0;
        float slowsum = 0.f;
#pragma unroll
        for (int r = 0; r < 4; ++r) {
            unsigned long long mr = __ballot((s < NS) && (bnd[r] < BND_THR));
            nslow += (int)__popcll(mr);
            while (mr) {
                int src = (int)__ffsll(mr) - 1; mr &= (mr - 1);
                int ss = src & 15;
                int rrow = tile * 16 + (src >> 4) * 4 + r;
                const float* xq = x + (size_t)rrow * DIN;
                const float* yq = ws + WS_Y2 + ss * DIN;
                float a = 0.f;
                for (int i = lane; i < DIN; i += 64)
                    a -= __builtin_amdgcn_logf(
                        1.f + __builtin_amdgcn_exp2f((1.f - 2.f * xq[i]) * yq[i]));
#pragma unroll
                for (int off = 32; off > 0; off >>= 1) a += __shfl_xor(a, off);
                slowsum += __logf(__builtin_amdgcn_exp2f(a) + 0.001f);
            }
        }
        wsum = (float)(160 - nslow) * L001 + slowsum;
    }
    if (lane == 0) atomicAdd(&bsum, wsum);
    __syncthreads();

    if (tid == 0) {
        atomicAdd(&ws[200], bsum);
        __threadfence();
        unsigned old = atomicAdd((unsigned*)&ws[203], 1u);
        if (old == (unsigned)(nblocks - 1)) lastflag = 1;
    }
    __syncthreads();
    if (lastflag) {
        __threadfence();
        float contrib = 0.f;
        if (tid < DZ) {
            const float inv = 1.f / (float)NROWS;
            float mm = ws[tid] * inv;
            float cc = ws[100 + tid] * inv;
            contrib = 0.5f * __logf(cc);
#pragma unroll
            for (int ss2 = 0; ss2 < NS; ++ss2) {
                float e = eps[ss2 * DZ + tid];
                float zz = mm + cc * e;
                contrib += (0.5f * cc * e * e - 0.5f * zz * zz) * (1.f / NS);
            }
        }
        dred[tid] = contrib;
        __syncthreads();
        for (int off = 128; off > 0; off >>= 1) {
            if (tid < off) dred[tid] += dred[tid + off];
            __syncthreads();
        }
        if (tid == 0) {
            float S = atomicAdd(&ws[200], 0.f);
            float E = S * (1.f / ((float)NROWS * (float)NS));
            out[0] = -(E + dred[0]);
        }
    }
}

extern "C" void kernel_launch(void* const* d_in, const int* in_sizes, int n_in,
                              void* d_out, int out_size, void* d_ws, size_t ws_size,
                              hipStream_t stream)
{
    const float* x   = (const float*)d_in[0];
    const float* W0  = (const float*)d_in[1];
    const float* b0  = (const float*)d_in[2];
    const float* W1  = (const float*)d_in[3];
    const float* b1  = (const float*)d_in[4];
    const float* W2  = (const float*)d_in[5];
    const float* b2  = (const float*)d_in[6];
    const float* eps = (const float*)d_in[7];
    float* out = (float*)d_out;
    float* ws  = (float*)d_ws;
    ushort_t* Wb = (ushort_t*)((char*)d_ws + WB_OFF_BYTES);

    wb_kernel<<<(KTILES * NCT * 64 + 255) / 256, 256, 0, stream>>>(W0, W1, Wb, ws);
    colmean_k<<<256, 1024, 0, stream>>>(x, Wb, b0, b1, ws);
    y2z_kernel<<<(NS * DIN * 64) / 256, 256, 0, stream>>>(W2, b2, eps, ws);
    pv_final_kernel<<<256, 256, 0, stream>>>(x, ws, eps, out, 256);
}

// Round 19
// 51.790 us; speedup vs baseline: 1.1828x; 1.0421x over previous
//
#include <hip/hip_runtime.h>
#include <hip/hip_bf16.h>
#include <math.h>

#define NROWS 16384
#define DIN   784
#define DZ    100
#define NS    10
#define NCT   16           // 16 col-tiles x 16 = 256 cols (200 real + 56 zero pad)
#define KTILES 25          // 25 * 32 = 800 >= 784, tail frags zeroed
#define BND_THR 45.0f
#define KTPAD 520          // kt-stride in ushorts (1040B)

typedef unsigned short ushort_t;
typedef short bf16x8 __attribute__((ext_vector_type(8)));
typedef float f32x4  __attribute__((ext_vector_type(4)));

// ws: [0..199] colsums (atomic)  [200] pv sum  [203] done-counter
//     [208..8047] y2[s][i] = y*log2e
// byte 64KB..: Wb bf16 frag-swizzled W (400 KB)
#define WS_Y2 208
#define WB_OFF_BYTES (64u * 1024u)

__device__ __forceinline__ float softplus_fast(float v) {
    // ln(1+e^v) = (max(t,0) + log2(1+2^-|t|)) * ln2, t = v*log2e
    float t = v * 1.44269504088896f;
    return (fmaxf(t, 0.f)
            + __builtin_amdgcn_logf(1.f + __builtin_amdgcn_exp2f(-fabsf(t))))
           * 0.69314718055995f;
}
__device__ __forceinline__ unsigned pack2(float lo, float hi) {
    float2 f2; f2.x = lo; f2.y = hi;
    __hip_bfloat162 h2 = __float22bfloat162_rn(f2);
    return *reinterpret_cast<unsigned*>(&h2);
}

// ---- W -> bf16 B-frags + ws zero ----
// Wb[((kt*16 + ct)*64 + l)*8 + j] = W[ct*16 + (l&15)][kt*32 + (l>>4)*8 + j]
__global__ __launch_bounds__(256) void wb_kernel(
    const float* __restrict__ W0, const float* __restrict__ W1,
    ushort_t* __restrict__ Wb, float* __restrict__ ws)
{
    if (blockIdx.x == 0) ws[threadIdx.x] = 0.f;    // sums + counters
    int t = blockIdx.x * 256 + threadIdx.x;
    if (t >= KTILES * NCT * 64) return;
    int kt = t >> 10;
    int r  = t & 1023;
    int ct = r >> 6, l = r & 63;
    int col = ct * 16 + (l & 15);
    int k0  = kt * 32 + (l >> 4) * 8;
    uint4 o = make_uint4(0u, 0u, 0u, 0u);
    if (col < 200 && k0 < DIN) {
        const float* src = (col < 100 ? W0 + (size_t)col * DIN
                                      : W1 + (size_t)(col - 100) * DIN) + k0;
        float4 a = *(const float4*)src;
        float4 b = *(const float4*)(src + 4);
        o.x = pack2(a.x, a.y); o.y = pack2(a.z, a.w);
        o.z = pack2(b.x, b.y); o.w = pack2(b.z, b.w);
    }
    *(uint4*)(Wb + (size_t)t * 8) = o;
}

// ---- colmean h2: R16's B-stationary kernel with BATCH-ISSUED stage ----
// 256 blocks x 1024 thr (16 waves). Wave w owns col-tile w for ALL 4 rowtiles.
// Stage: all ~13 global float4 loads issued back-to-back (static unroll),
// THEN pack+ds_write -> one HBM-latency exposure instead of seven. One barrier.
// K-loop: zero barriers, named reg dbuf, 1 B-load + 4 ds_read + 4 MFMA per kt.
__global__ __launch_bounds__(1024) void colmean_h2(
    const float* __restrict__ x, const ushort_t* __restrict__ Wb,
    const float* __restrict__ b0, const float* __restrict__ b1,
    float* __restrict__ ws)
{
    __shared__ ushort_t xls[4 * KTILES * KTPAD];   // 104 KB
    const int tid = threadIdx.x;
    const int lane = tid & 63, w = tid >> 6;
    const int row0 = blockIdx.x * 64;

    // ---- stage: batch-issue loads, then pack+write ----
    {
        float4 la[7], lb[7];
        int dof[7];
#pragma unroll
        for (int i = 0; i < 7; ++i) {
            int slot = tid + i * 1024;               // slot = r*100 + kt*4 + kc
            la[i] = make_float4(0.f, 0.f, 0.f, 0.f);
            lb[i] = la[i];
            dof[i] = -1;
            if (slot < 6400) {
                int r  = slot / 100;
                int sl = slot - r * 100;
                int kt = sl >> 2, kc = sl & 3;
                int k0 = kt * 32 + kc * 8;
                if (k0 + 8 <= DIN) {
                    const float* src = x + (size_t)(row0 + r) * DIN + k0;
                    la[i] = *(const float4*)src;
                    lb[i] = *(const float4*)(src + 4);
                }
                int l = (kc << 4) | (r & 15);
                dof[i] = ((r >> 4) * KTILES + kt) * KTPAD + l * 8;
            }
        }
#pragma unroll
        for (int i = 0; i < 7; ++i) {
            if (dof[i] >= 0) {
                uint4 o;
                o.x = pack2(la[i].x, la[i].y); o.y = pack2(la[i].z, la[i].w);
                o.z = pack2(lb[i].x, lb[i].y); o.w = pack2(lb[i].z, lb[i].w);
                *(uint4*)&xls[dof[i]] = o;
            }
        }
    }
    __syncthreads();

    // ---- K-loop: zero barriers, named reg dbuf, B stationary per wave ----
    const ushort_t* ap  = xls + lane * 8;                  // + rt*KTILES*KTPAD + kt*KTPAD
    const ushort_t* wbp = Wb + (size_t)w * 512 + lane * 8; // + kt*8192

    f32x4 acc0 = (f32x4){0.f,0.f,0.f,0.f}, acc1 = acc0, acc2 = acc0, acc3 = acc0;

    bf16x8 Aa[4], Ab[4];
    uint4  Ba, Bb;

    auto ld = [&](int kt, bf16x8 (&A)[4], uint4& B) {
#pragma unroll
        for (int rt = 0; rt < 4; ++rt)
            A[rt] = *(const bf16x8*)(ap + (size_t)rt * KTILES * KTPAD + (size_t)kt * KTPAD);
        B = *(const uint4*)(wbp + (size_t)kt * 8192);
    };
    auto cp = [&](const bf16x8 (&A)[4], const uint4& B) {
        bf16x8 bf = *(const bf16x8*)&B;
        acc0 = __builtin_amdgcn_mfma_f32_16x16x32_bf16(A[0], bf, acc0, 0, 0, 0);
        acc1 = __builtin_amdgcn_mfma_f32_16x16x32_bf16(A[1], bf, acc1, 0, 0, 0);
        acc2 = __builtin_amdgcn_mfma_f32_16x16x32_bf16(A[2], bf, acc2, 0, 0, 0);
        acc3 = __builtin_amdgcn_mfma_f32_16x16x32_bf16(A[3], bf, acc3, 0, 0, 0);
    };

    ld(0, Aa, Ba);
    for (int i = 0; i < 12; ++i) {
        ld(2 * i + 1, Ab, Bb);
        cp(Aa, Ba);
        ld(2 * i + 2, Aa, Ba);
        cp(Ab, Bb);
    }
    cp(Aa, Ba);                            // kt = 24

    // ---- epilogue: wave owns complete 64-row sums for its 16 cols ----
    const int j = w * 16 + (lane & 15);
    const float bias = (j < 100) ? b0[j] : ((j < 200) ? b1[j - 100] : 0.f);
    float v = 0.f;
#pragma unroll
    for (int r = 0; r < 4; ++r)
        v += softplus_fast(acc0[r] + bias) + softplus_fast(acc1[r] + bias)
           + softplus_fast(acc2[r] + bias) + softplus_fast(acc3[r] + bias);
    v += __shfl_xor(v, 16);
    v += __shfl_xor(v, 32);
    if ((lane >> 4) == 0 && j < 200) atomicAdd(&ws[j], v);
}

// ---- y2 = (z @ W2.T + b2) * log2e with z computed inline from colsums ----
__global__ __launch_bounds__(256) void y2z_kernel(
    const float* __restrict__ W2, const float* __restrict__ b2,
    const float* __restrict__ eps, float* __restrict__ ws)
{
    int wid  = (int)((blockIdx.x * 256 + threadIdx.x) >> 6);
    int lane = threadIdx.x & 63;
    if (wid >= NS * DIN) return;
    int s = wid / DIN, i = wid % DIN;
    const float inv = 1.f / (float)NROWS;
    const float* wr = W2 + (size_t)i * DZ;
    const float* er = eps + (size_t)s * DZ;
    float p = 0.f;
    for (int d = lane; d < DZ; d += 64) {
        float zd = inv * (ws[d] + ws[100 + d] * er[d]);
        p += zd * wr[d];
    }
#pragma unroll
    for (int off = 32; off > 0; off >>= 1) p += __shfl_xor(p, off);
    if (lane == 0) ws[WS_Y2 + wid] = (p + b2[i]) * 1.4426950408889634f;
}

// ---- pv + fused finalization (R16-proven, direct x) ----
// MFMA-certified bound: sum_i max(u,0) = 0.5*(n.y + |n|.|y|), u=(1-2x)*y2 (log2).
// bnd >= 45 => p < 2^-43 << ulp(0.001)/2 => term == ln(0.001) exactly.
__global__ __launch_bounds__(256, 4) void pv_final_kernel(
    const float* __restrict__ x, float* __restrict__ ws,
    const float* __restrict__ eps, float* __restrict__ out, int nblocks)
{
    __shared__ ushort_t yf[KTILES * 512];   // y2 B-frags (bf16)
    __shared__ ushort_t ya[KTILES * 512];   // |y2| B-frags
    __shared__ float bsum;
    __shared__ int lastflag;
    __shared__ float dred[256];
    const int tid = threadIdx.x;
    const int lane = tid & 63, w = tid >> 6;

    for (int idx = tid; idx < KTILES * 64; idx += 256) {
        int kt = idx >> 6, l = idx & 63;
        int ss = l & 15, k0 = kt * 32 + (l >> 4) * 8;
        uint4 o = make_uint4(0u, 0u, 0u, 0u), oa = o;
        if (ss < NS && k0 < DIN) {
            const float* src = ws + WS_Y2 + ss * DIN + k0;
            float4 a = *(const float4*)src, b = *(const float4*)(src + 4);
            o.x = pack2(a.x, a.y); o.y = pack2(a.z, a.w);
            o.z = pack2(b.x, b.y); o.w = pack2(b.z, b.w);
            oa.x = o.x & 0x7FFF7FFFu; oa.y = o.y & 0x7FFF7FFFu;
            oa.z = o.z & 0x7FFF7FFFu; oa.w = o.w & 0x7FFF7FFFu;
        }
        *(uint4*)(yf + (size_t)idx * 8) = o;
        *(uint4*)(ya + (size_t)idx * 8) = oa;
    }
    if (tid == 0) { bsum = 0.f; lastflag = 0; }
    __syncthreads();

    const int tile = blockIdx.x * 4 + w;       // 1024 tiles of 16 rows
    const int row  = tile * 16 + (lane & 15);
    const int kc   = lane >> 4;
    const int s    = lane & 15;
    const float* xp = x + (size_t)row * DIN;
    const float L001 = -6.90775527898f;        // ln(0.001f)

    f32x4 acc0 = (f32x4){0.f, 0.f, 0.f, 0.f};
    f32x4 acc1 = (f32x4){0.f, 0.f, 0.f, 0.f};
    float4 a0A, a1A, a0B, a1B;

    auto loadA = [&](int kt, float4& a0, float4& a1) {
        int k0 = kt * 32 + kc * 8;
        if (k0 + 8 > DIN) k0 = 768;            // junk ok: y frags zero there
        a0 = *(const float4*)(xp + k0);
        a1 = *(const float4*)(xp + k0 + 4);
    };
    auto comp = [&](int kt, const float4& a0, const float4& a1) {
        bf16x8 nf; unsigned* p = (unsigned*)&nf;
        p[0] = pack2(1.f - 2.f * a0.x, 1.f - 2.f * a0.y);
        p[1] = pack2(1.f - 2.f * a0.z, 1.f - 2.f * a0.w);
        p[2] = pack2(1.f - 2.f * a1.x, 1.f - 2.f * a1.y);
        p[3] = pack2(1.f - 2.f * a1.z, 1.f - 2.f * a1.w);
        bf16x8 na; unsigned* q = (unsigned*)&na;
        q[0] = p[0] & 0x7FFF7FFFu; q[1] = p[1] & 0x7FFF7FFFu;
        q[2] = p[2] & 0x7FFF7FFFu; q[3] = p[3] & 0x7FFF7FFFu;
        bf16x8 fy = *(const bf16x8*)(yf + (size_t)kt * 512 + lane * 8);
        bf16x8 fa = *(const bf16x8*)(ya + (size_t)kt * 512 + lane * 8);
        acc0 = __builtin_amdgcn_mfma_f32_16x16x32_bf16(nf, fy, acc0, 0, 0, 0);
        acc1 = __builtin_amdgcn_mfma_f32_16x16x32_bf16(na, fa, acc1, 0, 0, 0);
    };
    loadA(0, a0A, a1A);
    for (int i = 0; i < 12; ++i) {
        loadA(2 * i + 1, a0B, a1B);
        comp(2 * i, a0A, a1A);
        loadA(2 * i + 2, a0A, a1A);
        comp(2 * i + 1, a0B, a1B);
    }
    comp(24, a0A, a1A);

    float bnd[4];
#pragma unroll
    for (int r = 0; r < 4; ++r) bnd[r] = 0.5f * (acc0[r] + acc1[r]);
    float wsum;
    bool lslow = (s < NS) &&
        (fminf(fminf(bnd[0], bnd[1]), fminf(bnd[2], bnd[3])) < BND_THR);
    unsigned long long m = __ballot(lslow);
    if (m == 0ull) {
        wsum = 160.f * L001;                   // 16 rows x 10 samples, all certified
    } else {
        int nslow = 0;
        float slowsum = 0.f;
#pragma unroll
        for (int r = 0; r < 4; ++r) {
            unsigned long long mr = __ballot((s < NS) && (bnd[r] < BND_THR));
            nslow += (int)__popcll(mr);
            while (mr) {
                int src = (int)__ffsll(mr) - 1; mr &= (mr - 1);
                int ss = src & 15;
                int rrow = tile * 16 + (src >> 4) * 4 + r;
                const float* xq = x + (size_t)rrow * DIN;
                const float* yq = ws + WS_Y2 + ss * DIN;
                float a = 0.f;
                for (int i = lane; i < DIN; i += 64)
                    a -= __builtin_amdgcn_logf(
                        1.f + __builtin_amdgcn_exp2f((1.f - 2.f * xq[i]) * yq[i]));
#pragma unroll
                for (int off = 32; off > 0; off >>= 1) a += __shfl_xor(a, off);
                slowsum += __logf(__builtin_amdgcn_exp2f(a) + 0.001f);
            }
        }
        wsum = (float)(160 - nslow) * L001 + slowsum;
    }
    if (lane == 0) atomicAdd(&bsum, wsum);
    __syncthreads();

    if (tid == 0) {
        atomicAdd(&ws[200], bsum);
        __threadfence();
        unsigned old = atomicAdd((unsigned*)&ws[203], 1u);
        if (old == (unsigned)(nblocks - 1)) lastflag = 1;
    }
    __syncthreads();
    if (lastflag) {
        __threadfence();
        float contrib = 0.f;
        if (tid < DZ) {
            const float inv = 1.f / (float)NROWS;
            float mm = ws[tid] * inv;
            float cc = ws[100 + tid] * inv;
            contrib = 0.5f * __logf(cc);
#pragma unroll
            for (int ss2 = 0; ss2 < NS; ++ss2) {
                float e = eps[ss2 * DZ + tid];
                float zz = mm + cc * e;
                contrib += (0.5f * cc * e * e - 0.5f * zz * zz) * (1.f / NS);
            }
        }
        dred[tid] = contrib;
        __syncthreads();
        for (int off = 128; off > 0; off >>= 1) {
            if (tid < off) dred[tid] += dred[tid + off];
            __syncthreads();
        }
        if (tid == 0) {
            float S = atomicAdd(&ws[200], 0.f);
            float E = S * (1.f / ((float)NROWS * (float)NS));
            out[0] = -(E + dred[0]);
        }
    }
}

extern "C" void kernel_launch(void* const* d_in, const int* in_sizes, int n_in,
                              void* d_out, int out_size, void* d_ws, size_t ws_size,
                              hipStream_t stream)
{
    const float* x   = (const float*)d_in[0];
    const float* W0  = (const float*)d_in[1];
    const float* b0  = (const float*)d_in[2];
    const float* W1  = (const float*)d_in[3];
    const float* b1  = (const float*)d_in[4];
    const float* W2  = (const float*)d_in[5];
    const float* b2  = (const float*)d_in[6];
    const float* eps = (const float*)d_in[7];
    float* out = (float*)d_out;
    float* ws  = (float*)d_ws;
    ushort_t* Wb = (ushort_t*)((char*)d_ws + WB_OFF_BYTES);

    wb_kernel<<<(KTILES * NCT * 64 + 255) / 256, 256, 0, stream>>>(W0, W1, Wb, ws);
    colmean_h2<<<NROWS / 64, 1024, 0, stream>>>(x, Wb, b0, b1, ws);
    y2z_kernel<<<(NS * DIN * 64) / 256, 256, 0, stream>>>(W2, b2, eps, ws);
    pv_final_kernel<<<256, 256, 0, stream>>>(x, ws, eps, out, 256);
}